// Round 4
// baseline (224.262 us; speedup 1.0000x reference)
//
#include <hip/hip_runtime.h>
#include <hip/hip_bf16.h>
#include <math.h>

typedef short short8 __attribute__((ext_vector_type(8)));
typedef short short4v __attribute__((ext_vector_type(4)));
typedef float f32x4 __attribute__((ext_vector_type(4)));

#define NE 500000
#define ND 128
#define NNODES 100000
#define NT ((NE + 63) / 64)          // 7813 tiles of 64 edges
#define TPB 8                        // tiles per block (pipeline depth)

static __device__ __forceinline__ unsigned short f2bf(float f) {
    unsigned u = __builtin_bit_cast(unsigned, f);
    u += 0x7FFFu + ((u >> 16) & 1u);   // round-to-nearest-even
    return (unsigned short)(u >> 16);
}
static __device__ __forceinline__ float bf2f(unsigned short h) {
    return __builtin_bit_cast(float, (unsigned)h << 16);
}

// W1 [K=256][N=256] f32  ->  W1T [N=256][K=256] bf16 (k-contiguous rows)
__global__ void prep_w1t_kernel(const float* __restrict__ W1,
                                unsigned short* __restrict__ W1T) {
    int i = blockIdx.x * blockDim.x + threadIdx.x;   // 0..65535
    int n = i >> 8, k = i & 255;
    W1T[n * 256 + k] = f2bf(W1[k * 256 + n]);
}

// z, z2 f32 -> bf16 mirrors (8 elems/thread)
__global__ __launch_bounds__(256) void prep_zbf_kernel(
    const float* __restrict__ z, const float* __restrict__ z2,
    unsigned short* __restrict__ zbf, unsigned short* __restrict__ z2bf) {
    long t = (long)blockIdx.x * 256 + threadIdx.x;   // 0..3,199,999
    const float* src; unsigned short* dst; long off;
    const long half = (long)NNODES * ND / 8;         // 1,600,000
    if (t < half) { src = z;  dst = zbf;  off = t * 8; }
    else          { src = z2; dst = z2bf; off = (t - half) * 8; }
    float4 a = *reinterpret_cast<const float4*>(src + off);
    float4 b = *reinterpret_cast<const float4*>(src + off + 4);
    short8 v;
    v[0] = (short)f2bf(a.x); v[1] = (short)f2bf(a.y);
    v[2] = (short)f2bf(a.z); v[3] = (short)f2bf(a.w);
    v[4] = (short)f2bf(b.x); v[5] = (short)f2bf(b.y);
    v[6] = (short)f2bf(b.z); v[7] = (short)f2bf(b.w);
    *reinterpret_cast<short8*>(dst + off) = v;
}

#define PUBLISH_BARRIER() do { \
    asm volatile("s_waitcnt lgkmcnt(0)" ::: "memory"); \
    __builtin_amdgcn_s_barrier(); } while (0)

// Pipelined persistent kernel: TPB tiles/block, gathers for t+1 in flight
// across raw barriers while MFMA+epilogue of t runs.
__global__ __launch_bounds__(256, 2) void edge_mlp_pipe(
    const unsigned short* __restrict__ zbf, const unsigned short* __restrict__ z2bf,
    const int* __restrict__ edge,
    const unsigned short* __restrict__ w1t,
    const float* __restrict__ b1, const float* __restrict__ W2,
    const float* __restrict__ b2, float* __restrict__ out)
{
    __shared__ unsigned short xs[64 * 256];   // 32 KB, XOR-swizzled bf16 x-tile
    __shared__ float partials[4][64];

    const int tid = threadIdx.x;
    const int lane = tid & 63;
    const int wv = tid >> 6;
    const int l15 = lane & 15;
    const int l4 = lane >> 4;
    const int l5 = lane >> 5;            // which edge of the pair
    const int half = (lane >> 4) & 1;    // z vs z2
    const int c8 = lane & 15;            // 8-col chunk within the row
    const unsigned short* gbase = half ? z2bf : zbf;

    // loop-invariant epilogue params
    float b1v[4], w2v[4];
#pragma unroll
    for (int n = 0; n < 4; ++n) {
        int col = wv * 64 + n * 16 + l15;
        b1v[n] = b1[col];
        w2v[n] = W2[col];
    }
    const float bias2 = b2[0];

    const int t0 = blockIdx.x * TPB;
    const int tend = (t0 + TPB < NT) ? (t0 + TPB) : NT;

    short8 vs[8], vd[8];
    int si_nxt, di_nxt;

    // ---- prologue: idx(t0) -> gathers(t0); idx(t0+1) ----
    {
        long e = (long)t0 * 64 + lane; if (e >= NE) e = NE - 1;
        int si = edge[e], di = edge[NE + e];
#pragma unroll
        for (int i = 0; i < 8; ++i) {
            int el = (wv << 4) + (i << 1) + l5;
            long s = __shfl(si, el, 64);
            long d = __shfl(di, el, 64);
            vs[i] = *reinterpret_cast<const short8*>(gbase + s * ND + (c8 << 3));
            vd[i] = *reinterpret_cast<const short8*>(gbase + d * ND + (c8 << 3));
        }
        long t1 = (t0 + 1 < NT) ? (t0 + 1) : (NT - 1);
        long e1 = t1 * 64 + lane; if (e1 >= NE) e1 = NE - 1;
        si_nxt = edge[e1]; di_nxt = edge[NE + e1];
    }

    for (int t = t0; t < tend; ++t) {
        // ---- 1. multiply + cvt -> swizzled bf16 x-tile in LDS ----
#pragma unroll
        for (int i = 0; i < 8; ++i) {
            int el = (wv << 4) + (i << 1) + l5;
            short8 p;
#pragma unroll
            for (int j = 0; j < 8; ++j)
                p[j] = (short)f2bf(bf2f((unsigned short)vs[i][j]) *
                                   bf2f((unsigned short)vd[i][j]));
            int col0 = (half << 7) + (c8 << 3);
            *reinterpret_cast<short8*>(&xs[el * 256 + (col0 ^ ((el & 7) << 3))]) = p;
        }

        // ---- 2. issue gathers(t+1) + idx loads(t+2); stay in flight across
        //         the barriers below (raw s_barrier does NOT drain vmcnt) ----
        if (t + 1 < tend) {
#pragma unroll
            for (int i = 0; i < 8; ++i) {
                int el = (wv << 4) + (i << 1) + l5;
                long s = __shfl(si_nxt, el, 64);
                long d = __shfl(di_nxt, el, 64);
                vs[i] = *reinterpret_cast<const short8*>(gbase + s * ND + (c8 << 3));
                vd[i] = *reinterpret_cast<const short8*>(gbase + d * ND + (c8 << 3));
            }
            long t2 = ((long)t + 2 < NT) ? (t + 2) : (NT - 1);
            long e2 = t2 * 64 + lane; if (e2 >= NE) e2 = NE - 1;
            si_nxt = edge[e2]; di_nxt = edge[NE + e2];
        }

        // ---- 3. publish x-tile ----
        PUBLISH_BARRIER();

        // ---- 4. X[64x256] @ W1[256x256]; per-wave 64x64 slice ----
        f32x4 acc[4][4];
#pragma unroll
        for (int m = 0; m < 4; ++m)
#pragma unroll
            for (int n = 0; n < 4; ++n)
                acc[m][n] = (f32x4){0.f, 0.f, 0.f, 0.f};

        const int ncol0 = wv * 64 + l15;
#pragma unroll
        for (int ks = 0; ks < 8; ++ks) {
            const int k0 = ks * 32 + l4 * 8;
            short8 a[4], b[4];
#pragma unroll
            for (int m = 0; m < 4; ++m) {
                int row = m * 16 + l15;
                a[m] = *reinterpret_cast<const short8*>(
                    &xs[row * 256 + (k0 ^ ((row & 7) << 3))]);
            }
#pragma unroll
            for (int n = 0; n < 4; ++n) {
                b[n] = *reinterpret_cast<const short8*>(
                    w1t + (long)(ncol0 + n * 16) * 256 + k0);
            }
#pragma unroll
            for (int m = 0; m < 4; ++m)
#pragma unroll
                for (int n = 0; n < 4; ++n)
                    acc[m][n] = __builtin_amdgcn_mfma_f32_16x16x32_bf16(
                        a[m], b[n], acc[m][n], 0, 0, 0);
        }

        // ---- 5. relu + dot(W2): 16-lane shuffle reduce -> partials ----
#pragma unroll
        for (int m = 0; m < 4; ++m) {
            float s0 = 0.f, s1 = 0.f, s2 = 0.f, s3 = 0.f;
#pragma unroll
            for (int n = 0; n < 4; ++n) {
                float h0 = fmaxf(acc[m][n][0] + b1v[n], 0.f);
                float h1 = fmaxf(acc[m][n][1] + b1v[n], 0.f);
                float h2 = fmaxf(acc[m][n][2] + b1v[n], 0.f);
                float h3 = fmaxf(acc[m][n][3] + b1v[n], 0.f);
                s0 += h0 * w2v[n]; s1 += h1 * w2v[n];
                s2 += h2 * w2v[n]; s3 += h3 * w2v[n];
            }
#pragma unroll
            for (int mask = 1; mask < 16; mask <<= 1) {
                s0 += __shfl_xor(s0, mask, 64);
                s1 += __shfl_xor(s1, mask, 64);
                s2 += __shfl_xor(s2, mask, 64);
                s3 += __shfl_xor(s3, mask, 64);
            }
            if (l15 == 0) {
                int rb = m * 16 + l4 * 4;
                partials[wv][rb + 0] = s0;
                partials[wv][rb + 1] = s1;
                partials[wv][rb + 2] = s2;
                partials[wv][rb + 3] = s3;
            }
        }
        PUBLISH_BARRIER();

        // ---- 6. combine + sigmoid + store ----
        if (tid < 64) {
            float p = partials[0][tid] + partials[1][tid]
                    + partials[2][tid] + partials[3][tid] + bias2;
            long e = (long)t * 64 + tid;
            if (e < NE) out[e] = 1.0f / (1.0f + expf(-p));
        }
        __builtin_amdgcn_s_barrier();   // partials/xs free for next tile
    }
}

// f32 fallback (only if d_ws can't hold the bf16 mirrors) — simple version
__global__ __launch_bounds__(256) void edge_mlp_f32(
    const float* __restrict__ z, const float* __restrict__ z2,
    const int* __restrict__ edge,
    const unsigned short* __restrict__ w1t,
    const float* __restrict__ b1, const float* __restrict__ W2,
    const float* __restrict__ b2, float* __restrict__ out)
{
    __shared__ unsigned short xs[64 * 256];
    __shared__ float partials[4][64];
    const int tid = threadIdx.x, lane = tid & 63, wv = tid >> 6;
    const int l15 = lane & 15, l4 = lane >> 4;
    const long eb0 = (long)blockIdx.x * 64;
    {
        const int halfz = lane >> 5, c4 = lane & 31;
        const float* base = halfz ? z2 : z;
        long e = eb0 + ((tid >> 2) & 63); (void)e;
        for (int i = 0; i < 16; ++i) {
            int el = (wv << 4) + i;
            long ee = eb0 + el; if (ee >= NE) ee = NE - 1;
            long s = edge[ee], d = edge[NE + ee];
            float4 a = *reinterpret_cast<const float4*>(base + s * ND + (c4 << 2));
            float4 b = *reinterpret_cast<const float4*>(base + d * ND + (c4 << 2));
            short4v p;
            p[0] = (short)f2bf(a.x * b.x); p[1] = (short)f2bf(a.y * b.y);
            p[2] = (short)f2bf(a.z * b.z); p[3] = (short)f2bf(a.w * b.w);
            int col0 = (halfz << 7) + (c4 << 2);
            *reinterpret_cast<short4v*>(&xs[el * 256 + (col0 ^ ((el & 7) << 3))]) = p;
        }
    }
    __syncthreads();
    f32x4 acc[4][4];
    for (int m = 0; m < 4; ++m) for (int n = 0; n < 4; ++n) acc[m][n] = (f32x4){0,0,0,0};
    const int ncol0 = wv * 64 + l15;
    for (int ks = 0; ks < 8; ++ks) {
        const int k0 = ks * 32 + l4 * 8;
        short8 a[4], b[4];
        for (int m = 0; m < 4; ++m) {
            int row = m * 16 + l15;
            a[m] = *reinterpret_cast<const short8*>(&xs[row * 256 + (k0 ^ ((row & 7) << 3))]);
        }
        for (int n = 0; n < 4; ++n)
            b[n] = *reinterpret_cast<const short8*>(w1t + (long)(ncol0 + n * 16) * 256 + k0);
        for (int m = 0; m < 4; ++m) for (int n = 0; n < 4; ++n)
            acc[m][n] = __builtin_amdgcn_mfma_f32_16x16x32_bf16(a[m], b[n], acc[m][n], 0, 0, 0);
    }
    float b1v[4], w2v[4];
    for (int n = 0; n < 4; ++n) {
        int col = wv * 64 + n * 16 + l15;
        b1v[n] = b1[col]; w2v[n] = W2[col];
    }
    for (int m = 0; m < 4; ++m) {
        float s0 = 0, s1 = 0, s2 = 0, s3 = 0;
        for (int n = 0; n < 4; ++n) {
            float h0 = fmaxf(acc[m][n][0] + b1v[n], 0.f), h1 = fmaxf(acc[m][n][1] + b1v[n], 0.f);
            float h2 = fmaxf(acc[m][n][2] + b1v[n], 0.f), h3 = fmaxf(acc[m][n][3] + b1v[n], 0.f);
            s0 += h0 * w2v[n]; s1 += h1 * w2v[n]; s2 += h2 * w2v[n]; s3 += h3 * w2v[n];
        }
        for (int mask = 1; mask < 16; mask <<= 1) {
            s0 += __shfl_xor(s0, mask, 64); s1 += __shfl_xor(s1, mask, 64);
            s2 += __shfl_xor(s2, mask, 64); s3 += __shfl_xor(s3, mask, 64);
        }
        if (l15 == 0) {
            int rb = m * 16 + l4 * 4;
            partials[wv][rb] = s0; partials[wv][rb + 1] = s1;
            partials[wv][rb + 2] = s2; partials[wv][rb + 3] = s3;
        }
    }
    __syncthreads();
    if (tid < 64) {
        float p = partials[0][tid] + partials[1][tid] + partials[2][tid]
                + partials[3][tid] + b2[0];
        long e = eb0 + tid;
        if (e < NE) out[e] = 1.0f / (1.0f + expf(-p));
    }
}

extern "C" void kernel_launch(void* const* d_in, const int* in_sizes, int n_in,
                              void* d_out, int out_size, void* d_ws, size_t ws_size,
                              hipStream_t stream)
{
    const float* z  = (const float*)d_in[0];
    const float* z2 = (const float*)d_in[1];
    const int*  edge = (const int*)d_in[2];
    const float* W1 = (const float*)d_in[3];
    const float* b1 = (const float*)d_in[4];
    const float* W2 = (const float*)d_in[5];
    const float* b2 = (const float*)d_in[6];
    float* out = (float*)d_out;

    const size_t zbf_bytes = (size_t)NNODES * ND * 2;        // 25.6 MB each
    const size_t need = 2 * zbf_bytes + 256 * 256 * 2;       // + w1t
    const bool usebf16 = (ws_size >= need);

    unsigned short* zbf  = (unsigned short*)d_ws;
    unsigned short* z2bf = (unsigned short*)((char*)d_ws + zbf_bytes);
    unsigned short* w1t  = usebf16
        ? (unsigned short*)((char*)d_ws + 2 * zbf_bytes)
        : (unsigned short*)d_ws;

    prep_w1t_kernel<<<256, 256, 0, stream>>>(W1, w1t);
    if (usebf16) {
        prep_zbf_kernel<<<12500, 256, 0, stream>>>(z, z2, zbf, z2bf);
        const int nblk = (NT + TPB - 1) / TPB;   // 977
        edge_mlp_pipe<<<nblk, 256, 0, stream>>>(
            zbf, z2bf, edge, w1t, b1, W2, b2, out);
    } else {
        edge_mlp_f32<<<NT, 256, 0, stream>>>(
            z, z2, edge, w1t, b1, W2, b2, out);
    }
}

// Round 5
// 177.667 us; speedup vs baseline: 1.2623x; 1.2623x over previous
//
#include <hip/hip_runtime.h>
#include <hip/hip_bf16.h>
#include <math.h>

typedef short short8 __attribute__((ext_vector_type(8)));
typedef short short4v __attribute__((ext_vector_type(4)));
typedef float f32x4 __attribute__((ext_vector_type(4)));

#define NE 500000
#define ND 128
#define NNODES 100000
#define NT ((NE + 63) / 64)          // 7813 tiles of 64 edges
#define TPB 8                        // tiles per block

static __device__ __forceinline__ unsigned short f2bf(float f) {
    unsigned u = __builtin_bit_cast(unsigned, f);
    u += 0x7FFFu + ((u >> 16) & 1u);   // round-to-nearest-even
    return (unsigned short)(u >> 16);
}
static __device__ __forceinline__ float bf2f(unsigned short h) {
    return __builtin_bit_cast(float, (unsigned)h << 16);
}

// W1 [K=256][N=256] f32  ->  W1T [N=256][K=256] bf16 (k-contiguous rows)
__global__ void prep_w1t_kernel(const float* __restrict__ W1,
                                unsigned short* __restrict__ W1T) {
    int i = blockIdx.x * blockDim.x + threadIdx.x;   // 0..65535
    int n = i >> 8, k = i & 255;
    W1T[n * 256 + k] = f2bf(W1[k * 256 + n]);
}

// z, z2 f32 -> bf16 mirrors (8 elems/thread)
__global__ __launch_bounds__(256) void prep_zbf_kernel(
    const float* __restrict__ z, const float* __restrict__ z2,
    unsigned short* __restrict__ zbf, unsigned short* __restrict__ z2bf) {
    long t = (long)blockIdx.x * 256 + threadIdx.x;   // 0..3,199,999
    const float* src; unsigned short* dst; long off;
    const long half = (long)NNODES * ND / 8;         // 1,600,000
    if (t < half) { src = z;  dst = zbf;  off = t * 8; }
    else          { src = z2; dst = z2bf; off = (t - half) * 8; }
    float4 a = *reinterpret_cast<const float4*>(src + off);
    float4 b = *reinterpret_cast<const float4*>(src + off + 4);
    short8 v;
    v[0] = (short)f2bf(a.x); v[1] = (short)f2bf(a.y);
    v[2] = (short)f2bf(a.z); v[3] = (short)f2bf(a.w);
    v[4] = (short)f2bf(b.x); v[5] = (short)f2bf(b.y);
    v[6] = (short)f2bf(b.z); v[7] = (short)f2bf(b.w);
    *reinterpret_cast<short8*>(dst + off) = v;
}

#define PUBLISH_BARRIER() do { \
    asm volatile("s_waitcnt lgkmcnt(0)" ::: "memory"); \
    __builtin_amdgcn_s_barrier(); } while (0)

// 8-wave pipelined kernel. B-fragments of W1T live in registers for the whole
// block, so the tile loop has NO global loads except the gathers -> vmcnt
// ordering cannot stall MFMA on in-flight prefetches.
__global__ __launch_bounds__(512, 2) void edge_mlp_pipe8(
    const unsigned short* __restrict__ zbf, const unsigned short* __restrict__ z2bf,
    const int* __restrict__ edge,
    const unsigned short* __restrict__ w1t,
    const float* __restrict__ b1, const float* __restrict__ W2,
    const float* __restrict__ b2, float* __restrict__ out)
{
    __shared__ unsigned short xs[64 * 256];   // 32 KB swizzled bf16 x-tile
    __shared__ float partials[8][64];         // 2 KB

    const int tid = threadIdx.x;
    const int lane = tid & 63;
    const int wv = tid >> 6;             // 0..7; owns cols [wv*32, wv*32+32)
    const int l15 = lane & 15;
    const int l4 = lane >> 4;
    const int l5 = lane >> 5;            // which edge of the pair
    const int half = (lane >> 4) & 1;    // z vs z2
    const int c8 = lane & 15;            // 8-elem chunk within the row
    const unsigned short* gbase = half ? z2bf : zbf;

    // ---- one-time: B fragments (wave's 32 cols x K=256) into registers ----
    short8 breg[2][8];
#pragma unroll
    for (int n = 0; n < 2; ++n)
#pragma unroll
        for (int ks = 0; ks < 8; ++ks)
            breg[n][ks] = *reinterpret_cast<const short8*>(
                w1t + (long)(wv * 32 + n * 16 + l15) * 256 + ks * 32 + l4 * 8);

    float b1v[2], w2v[2];
#pragma unroll
    for (int n = 0; n < 2; ++n) {
        int col = wv * 32 + n * 16 + l15;
        b1v[n] = b1[col];
        w2v[n] = W2[col];
    }
    const float bias2 = b2[0];

    const int t0 = blockIdx.x * TPB;
    const int tend = (t0 + TPB < NT) ? (t0 + TPB) : NT;

    short8 vs[4], vd[4];
    int si_cur, di_cur;   // edge indices for tile t+1

    // ---- prologue: idx(t0) -> gathers(t0); idx(t0+1) ----
    {
        long e = (long)t0 * 64 + wv * 8 + (lane & 7); if (e >= NE) e = NE - 1;
        int si = edge[e], di = edge[NE + e];
#pragma unroll
        for (int i = 0; i < 4; ++i) {
            int el_loc = i * 2 + l5;             // 0..7
            long s = __shfl(si, el_loc, 64);
            long d = __shfl(di, el_loc, 64);
            vs[i] = *reinterpret_cast<const short8*>(gbase + s * ND + (c8 << 3));
            vd[i] = *reinterpret_cast<const short8*>(gbase + d * ND + (c8 << 3));
        }
        int t1 = (t0 + 1 < NT) ? t0 + 1 : NT - 1;
        long e1 = (long)t1 * 64 + wv * 8 + (lane & 7); if (e1 >= NE) e1 = NE - 1;
        si_cur = edge[e1]; di_cur = edge[NE + e1];
    }

    for (int t = t0; t < tend; ++t) {
        // ---- 1. multiply + cvt -> swizzled x-tile rows [wv*8, wv*8+8) ----
#pragma unroll
        for (int i = 0; i < 4; ++i) {
            int el = wv * 8 + i * 2 + l5;
            short8 p;
#pragma unroll
            for (int j = 0; j < 8; ++j)
                p[j] = (short)f2bf(bf2f((unsigned short)vs[i][j]) *
                                   bf2f((unsigned short)vd[i][j]));
            int col0 = (half << 7) + (c8 << 3);
            *reinterpret_cast<short8*>(&xs[el * 256 + (col0 ^ ((el & 7) << 3))]) = p;
        }

        // ---- 2. issue gathers(t+1) + idx(t+2); stay in flight across
        //         the MFMA phase (no global loads there to force a drain) ----
        if (t + 1 < tend) {
#pragma unroll
            for (int i = 0; i < 4; ++i) {
                int el_loc = i * 2 + l5;
                long s = __shfl(si_cur, el_loc, 64);
                long d = __shfl(di_cur, el_loc, 64);
                vs[i] = *reinterpret_cast<const short8*>(gbase + s * ND + (c8 << 3));
                vd[i] = *reinterpret_cast<const short8*>(gbase + d * ND + (c8 << 3));
            }
            int t2 = (t + 2 < NT) ? t + 2 : NT - 1;
            long e2 = (long)t2 * 64 + wv * 8 + (lane & 7); if (e2 >= NE) e2 = NE - 1;
            si_cur = edge[e2]; di_cur = edge[NE + e2];
        }

        // ---- 3. publish x-tile (lgkm only; vmcnt NOT drained) ----
        PUBLISH_BARRIER();

        // ---- 4. X[64x256] @ W1-slice; A from LDS, B from registers ----
        f32x4 acc[4][2];
#pragma unroll
        for (int m = 0; m < 4; ++m)
#pragma unroll
            for (int n = 0; n < 2; ++n)
                acc[m][n] = (f32x4){0.f, 0.f, 0.f, 0.f};

#pragma unroll
        for (int ks = 0; ks < 8; ++ks) {
            const int k0 = ks * 32 + l4 * 8;
            short8 a[4];
#pragma unroll
            for (int m = 0; m < 4; ++m) {
                int row = m * 16 + l15;
                a[m] = *reinterpret_cast<const short8*>(
                    &xs[row * 256 + (k0 ^ ((row & 7) << 3))]);
            }
#pragma unroll
            for (int m = 0; m < 4; ++m)
#pragma unroll
                for (int n = 0; n < 2; ++n)
                    acc[m][n] = __builtin_amdgcn_mfma_f32_16x16x32_bf16(
                        a[m], breg[n][ks], acc[m][n], 0, 0, 0);
        }

        // ---- 5. relu + dot(W2): 16-lane shuffle reduce -> partials ----
#pragma unroll
        for (int m = 0; m < 4; ++m) {
            float s0 = 0.f, s1 = 0.f, s2 = 0.f, s3 = 0.f;
#pragma unroll
            for (int n = 0; n < 2; ++n) {
                float h0 = fmaxf(acc[m][n][0] + b1v[n], 0.f);
                float h1 = fmaxf(acc[m][n][1] + b1v[n], 0.f);
                float h2 = fmaxf(acc[m][n][2] + b1v[n], 0.f);
                float h3 = fmaxf(acc[m][n][3] + b1v[n], 0.f);
                s0 += h0 * w2v[n]; s1 += h1 * w2v[n];
                s2 += h2 * w2v[n]; s3 += h3 * w2v[n];
            }
#pragma unroll
            for (int mask = 1; mask < 16; mask <<= 1) {
                s0 += __shfl_xor(s0, mask, 64);
                s1 += __shfl_xor(s1, mask, 64);
                s2 += __shfl_xor(s2, mask, 64);
                s3 += __shfl_xor(s3, mask, 64);
            }
            if (l15 == 0) {
                int rb = m * 16 + l4 * 4;
                partials[wv][rb + 0] = s0;
                partials[wv][rb + 1] = s1;
                partials[wv][rb + 2] = s2;
                partials[wv][rb + 3] = s3;
            }
        }
        PUBLISH_BARRIER();

        // ---- 6. combine + sigmoid + store ----
        if (tid < 64) {
            float p = partials[0][tid] + partials[1][tid]
                    + partials[2][tid] + partials[3][tid]
                    + partials[4][tid] + partials[5][tid]
                    + partials[6][tid] + partials[7][tid] + bias2;
            long e = (long)t * 64 + tid;
            if (e < NE) out[e] = 1.0f / (1.0f + expf(-p));
        }
        __builtin_amdgcn_s_barrier();   // xs/partials free for next tile
    }
}

// f32 fallback (only if d_ws can't hold the bf16 mirrors)
__global__ __launch_bounds__(256) void edge_mlp_f32(
    const float* __restrict__ z, const float* __restrict__ z2,
    const int* __restrict__ edge,
    const unsigned short* __restrict__ w1t,
    const float* __restrict__ b1, const float* __restrict__ W2,
    const float* __restrict__ b2, float* __restrict__ out)
{
    __shared__ unsigned short xs[64 * 256];
    __shared__ float partials[4][64];
    const int tid = threadIdx.x, lane = tid & 63, wv = tid >> 6;
    const int l15 = lane & 15, l4 = lane >> 4;
    const long eb0 = (long)blockIdx.x * 64;
    {
        const int halfz = lane >> 5, c4 = lane & 31;
        const float* base = halfz ? z2 : z;
        for (int i = 0; i < 16; ++i) {
            int el = (wv << 4) + i;
            long ee = eb0 + el; if (ee >= NE) ee = NE - 1;
            long s = edge[ee], d = edge[NE + ee];
            float4 a = *reinterpret_cast<const float4*>(base + s * ND + (c4 << 2));
            float4 b = *reinterpret_cast<const float4*>(base + d * ND + (c4 << 2));
            short4v p;
            p[0] = (short)f2bf(a.x * b.x); p[1] = (short)f2bf(a.y * b.y);
            p[2] = (short)f2bf(a.z * b.z); p[3] = (short)f2bf(a.w * b.w);
            int col0 = (halfz << 7) + (c4 << 2);
            *reinterpret_cast<short4v*>(&xs[el * 256 + (col0 ^ ((el & 7) << 3))]) = p;
        }
    }
    __syncthreads();
    f32x4 acc[4][4];
    for (int m = 0; m < 4; ++m) for (int n = 0; n < 4; ++n) acc[m][n] = (f32x4){0,0,0,0};
    const int ncol0 = wv * 64 + l15;
    for (int ks = 0; ks < 8; ++ks) {
        const int k0 = ks * 32 + l4 * 8;
        short8 a[4], b[4];
        for (int m = 0; m < 4; ++m) {
            int row = m * 16 + l15;
            a[m] = *reinterpret_cast<const short8*>(&xs[row * 256 + (k0 ^ ((row & 7) << 3))]);
        }
        for (int n = 0; n < 4; ++n)
            b[n] = *reinterpret_cast<const short8*>(w1t + (long)(ncol0 + n * 16) * 256 + k0);
        for (int m = 0; m < 4; ++m) for (int n = 0; n < 4; ++n)
            acc[m][n] = __builtin_amdgcn_mfma_f32_16x16x32_bf16(a[m], b[n], acc[m][n], 0, 0, 0);
    }
    float b1v[4], w2v[4];
    for (int n = 0; n < 4; ++n) {
        int col = wv * 64 + n * 16 + l15;
        b1v[n] = b1[col]; w2v[n] = W2[col];
    }
    for (int m = 0; m < 4; ++m) {
        float s0 = 0, s1 = 0, s2 = 0, s3 = 0;
        for (int n = 0; n < 4; ++n) {
            float h0 = fmaxf(acc[m][n][0] + b1v[n], 0.f), h1 = fmaxf(acc[m][n][1] + b1v[n], 0.f);
            float h2 = fmaxf(acc[m][n][2] + b1v[n], 0.f), h3 = fmaxf(acc[m][n][3] + b1v[n], 0.f);
            s0 += h0 * w2v[n]; s1 += h1 * w2v[n]; s2 += h2 * w2v[n]; s3 += h3 * w2v[n];
        }
        for (int mask = 1; mask < 16; mask <<= 1) {
            s0 += __shfl_xor(s0, mask, 64); s1 += __shfl_xor(s1, mask, 64);
            s2 += __shfl_xor(s2, mask, 64); s3 += __shfl_xor(s3, mask, 64);
        }
        if (l15 == 0) {
            int rb = m * 16 + l4 * 4;
            partials[wv][rb] = s0; partials[wv][rb + 1] = s1;
            partials[wv][rb + 2] = s2; partials[wv][rb + 3] = s3;
        }
    }
    __syncthreads();
    if (tid < 64) {
        float p = partials[0][tid] + partials[1][tid] + partials[2][tid]
                + partials[3][tid] + b2[0];
        long e = eb0 + tid;
        if (e < NE) out[e] = 1.0f / (1.0f + expf(-p));
    }
}

extern "C" void kernel_launch(void* const* d_in, const int* in_sizes, int n_in,
                              void* d_out, int out_size, void* d_ws, size_t ws_size,
                              hipStream_t stream)
{
    const float* z  = (const float*)d_in[0];
    const float* z2 = (const float*)d_in[1];
    const int*  edge = (const int*)d_in[2];
    const float* W1 = (const float*)d_in[3];
    const float* b1 = (const float*)d_in[4];
    const float* W2 = (const float*)d_in[5];
    const float* b2 = (const float*)d_in[6];
    float* out = (float*)d_out;

    const size_t zbf_bytes = (size_t)NNODES * ND * 2;        // 25.6 MB each
    const size_t need = 2 * zbf_bytes + 256 * 256 * 2;       // + w1t
    const bool usebf16 = (ws_size >= need);

    unsigned short* zbf  = (unsigned short*)d_ws;
    unsigned short* z2bf = (unsigned short*)((char*)d_ws + zbf_bytes);
    unsigned short* w1t  = usebf16
        ? (unsigned short*)((char*)d_ws + 2 * zbf_bytes)
        : (unsigned short*)d_ws;

    prep_w1t_kernel<<<256, 256, 0, stream>>>(W1, w1t);
    if (usebf16) {
        prep_zbf_kernel<<<12500, 256, 0, stream>>>(z, z2, zbf, z2bf);
        const int nblk = (NT + TPB - 1) / TPB;   // 977
        edge_mlp_pipe8<<<nblk, 512, 0, stream>>>(
            zbf, z2bf, edge, w1t, b1, W2, b2, out);
    } else {
        edge_mlp_f32<<<NT, 256, 0, stream>>>(
            z, z2, edge, w1t, b1, W2, b2, out);
    }
}

// Round 6
// 154.355 us; speedup vs baseline: 1.4529x; 1.1510x over previous
//
#include <hip/hip_runtime.h>
#include <hip/hip_bf16.h>
#include <math.h>

typedef _Float16 half8 __attribute__((ext_vector_type(8)));
typedef float f32x4 __attribute__((ext_vector_type(4)));

#define NE 500000
#define ND 128
#define NNODES 100000
#define NT ((NE + 63) / 64)          // 7813 tiles of 64 edges
#define TPB 8                        // tiles per block

// W1 [K=256][N=256] f32  ->  W1T [N=256][K=256] fp16 (k-contiguous rows)
__global__ void prep_w1t_kernel(const float* __restrict__ W1,
                                _Float16* __restrict__ W1T) {
    int i = blockIdx.x * blockDim.x + threadIdx.x;   // 0..65535
    int n = i >> 8, k = i & 255;
    W1T[n * 256 + k] = (_Float16)W1[k * 256 + n];
}

// z, z2 f32 -> fp16 mirrors (8 elems/thread)
__global__ __launch_bounds__(256) void prep_zh_kernel(
    const float* __restrict__ z, const float* __restrict__ z2,
    _Float16* __restrict__ zh, _Float16* __restrict__ z2h) {
    long t = (long)blockIdx.x * 256 + threadIdx.x;   // 0..3,199,999
    const float* src; _Float16* dst; long off;
    const long halfn = (long)NNODES * ND / 8;        // 1,600,000
    if (t < halfn) { src = z;  dst = zh;  off = t * 8; }
    else           { src = z2; dst = z2h; off = (t - halfn) * 8; }
    float4 a = *reinterpret_cast<const float4*>(src + off);
    float4 b = *reinterpret_cast<const float4*>(src + off + 4);
    half8 v;
    v[0] = (_Float16)a.x; v[1] = (_Float16)a.y;
    v[2] = (_Float16)a.z; v[3] = (_Float16)a.w;
    v[4] = (_Float16)b.x; v[5] = (_Float16)b.y;
    v[6] = (_Float16)b.z; v[7] = (_Float16)b.w;
    *reinterpret_cast<half8*>(dst + off) = v;
}

#define PUBLISH_BARRIER() do { \
    asm volatile("s_waitcnt lgkmcnt(0)" ::: "memory"); \
    __builtin_amdgcn_s_barrier(); } while (0)

// 8 waves as 2(m) x 4(n) grid. B (W1T) fully in registers (128 VGPR), fp16
// packed multiply in phase 1, vmem-clean MFMA phase, raw lgkm-only barriers.
__global__ __launch_bounds__(512, 1) void edge_mlp_pipe(
    const _Float16* __restrict__ zh, const _Float16* __restrict__ z2h,
    const int* __restrict__ edge,
    const _Float16* __restrict__ w1t,
    const float* __restrict__ b1, const float* __restrict__ W2,
    const float* __restrict__ b2, float* __restrict__ out)
{
    __shared__ _Float16 xs[64 * 256];   // 32 KB swizzled fp16 x-tile
    __shared__ float partials[4][64];   // 1 KB

    const int tid = threadIdx.x;
    const int lane = tid & 63;
    const int wv = tid >> 6;             // 0..7
    const int mi = wv >> 2;              // row half: rows [mi*32, mi*32+32)
    const int ni = wv & 3;               // col quarter: cols [ni*64, ni*64+64)
    const int l15 = lane & 15;
    const int l4 = lane >> 4;
    const int l5 = lane >> 5;            // which edge of the pair
    const int hz = (lane >> 4) & 1;      // z vs z2
    const int c8 = lane & 15;            // 8-elem chunk within the row
    const _Float16* gbase = hz ? z2h : zh;

    // ---- one-time: B fragments (wave's 64 cols x K=256) into registers ----
    half8 breg[4][8];
#pragma unroll
    for (int nf = 0; nf < 4; ++nf)
#pragma unroll
        for (int ks = 0; ks < 8; ++ks)
            breg[nf][ks] = *reinterpret_cast<const half8*>(
                w1t + (long)(ni * 64 + nf * 16 + l15) * 256 + ks * 32 + l4 * 8);

    float b1v[4], w2v[4];
#pragma unroll
    for (int nf = 0; nf < 4; ++nf) {
        int col = ni * 64 + nf * 16 + l15;
        b1v[nf] = b1[col];
        w2v[nf] = W2[col];
    }
    const float bias2 = b2[0];

    const int t0 = blockIdx.x * TPB;
    const int tend = (t0 + TPB < NT) ? (t0 + TPB) : NT;

    half8 vs[4], vd[4];
    int idx_nxt;

    // ---- prologue: idx(t0) -> gathers(t0); idx(t0+1) ----
    {
        long e = (long)t0 * 64 + wv * 8 + (lane & 7); if (e >= NE) e = NE - 1;
        int myidx = edge[((lane >> 3) & 1) ? (NE + e) : e];  // 0-7 src, 8-15 dst
#pragma unroll
        for (int i = 0; i < 4; ++i) {
            int el_loc = i * 2 + l5;
            long s = __shfl(myidx, el_loc, 64);
            long d = __shfl(myidx, 8 + el_loc, 64);
            vs[i] = *reinterpret_cast<const half8*>(gbase + s * ND + (c8 << 3));
            vd[i] = *reinterpret_cast<const half8*>(gbase + d * ND + (c8 << 3));
        }
        int t1 = (t0 + 1 < NT) ? t0 + 1 : NT - 1;
        long e1 = (long)t1 * 64 + wv * 8 + (lane & 7); if (e1 >= NE) e1 = NE - 1;
        idx_nxt = edge[((lane >> 3) & 1) ? (NE + e1) : e1];
    }

    for (int t = t0; t < tend; ++t) {
        // ---- 1. packed fp16 multiply -> swizzled x-tile rows ----
#pragma unroll
        for (int i = 0; i < 4; ++i) {
            int el = wv * 8 + i * 2 + l5;
            half8 p = vs[i] * vd[i];                    // 4x v_pk_mul_f16
            int col0 = (hz << 7) + (c8 << 3);
            *reinterpret_cast<half8*>(&xs[el * 256 + (col0 ^ ((el & 7) << 3))]) = p;
        }

        // ---- 2. issue gathers(t+1) + idx(t+2); stay in flight across MFMA ----
        if (t + 1 < tend) {
#pragma unroll
            for (int i = 0; i < 4; ++i) {
                int el_loc = i * 2 + l5;
                long s = __shfl(idx_nxt, el_loc, 64);
                long d = __shfl(idx_nxt, 8 + el_loc, 64);
                vs[i] = *reinterpret_cast<const half8*>(gbase + s * ND + (c8 << 3));
                vd[i] = *reinterpret_cast<const half8*>(gbase + d * ND + (c8 << 3));
            }
            int t2 = (t + 2 < NT) ? t + 2 : NT - 1;
            long e2 = (long)t2 * 64 + wv * 8 + (lane & 7); if (e2 >= NE) e2 = NE - 1;
            idx_nxt = edge[((lane >> 3) & 1) ? (NE + e2) : e2];
        }

        // ---- 3. publish x-tile (lgkm only; vmcnt NOT drained) ----
        PUBLISH_BARRIER();

        // ---- 4. X[64x256] @ W1-slice; A from LDS (2 frags), B from regs ----
        f32x4 acc[2][4];
#pragma unroll
        for (int mf = 0; mf < 2; ++mf)
#pragma unroll
            for (int nf = 0; nf < 4; ++nf)
                acc[mf][nf] = (f32x4){0.f, 0.f, 0.f, 0.f};

#pragma unroll
        for (int ks = 0; ks < 8; ++ks) {
            const int k0 = ks * 32 + l4 * 8;
            half8 a[2];
#pragma unroll
            for (int mf = 0; mf < 2; ++mf) {
                int row = mi * 32 + mf * 16 + l15;
                a[mf] = *reinterpret_cast<const half8*>(
                    &xs[row * 256 + (k0 ^ ((row & 7) << 3))]);
            }
#pragma unroll
            for (int mf = 0; mf < 2; ++mf)
#pragma unroll
                for (int nf = 0; nf < 4; ++nf)
                    acc[mf][nf] = __builtin_amdgcn_mfma_f32_16x16x32_f16(
                        a[mf], breg[nf][ks], acc[mf][nf], 0, 0, 0);
        }

        // ---- 5. relu + dot(W2): 16-lane shuffle reduce -> partials ----
#pragma unroll
        for (int mf = 0; mf < 2; ++mf) {
            float s0 = 0.f, s1 = 0.f, s2 = 0.f, s3 = 0.f;
#pragma unroll
            for (int nf = 0; nf < 4; ++nf) {
                float h0 = fmaxf(acc[mf][nf][0] + b1v[nf], 0.f);
                float h1 = fmaxf(acc[mf][nf][1] + b1v[nf], 0.f);
                float h2 = fmaxf(acc[mf][nf][2] + b1v[nf], 0.f);
                float h3 = fmaxf(acc[mf][nf][3] + b1v[nf], 0.f);
                s0 += h0 * w2v[nf]; s1 += h1 * w2v[nf];
                s2 += h2 * w2v[nf]; s3 += h3 * w2v[nf];
            }
#pragma unroll
            for (int mask = 1; mask < 16; mask <<= 1) {
                s0 += __shfl_xor(s0, mask, 64);
                s1 += __shfl_xor(s1, mask, 64);
                s2 += __shfl_xor(s2, mask, 64);
                s3 += __shfl_xor(s3, mask, 64);
            }
            if (l15 == 0) {
                int rb = mi * 32 + mf * 16 + l4 * 4;
                partials[ni][rb + 0] = s0;
                partials[ni][rb + 1] = s1;
                partials[ni][rb + 2] = s2;
                partials[ni][rb + 3] = s3;
            }
        }
        PUBLISH_BARRIER();

        // ---- 6. combine + sigmoid + store (next epilogue write is gated by
        //         the NEXT tile's barrier #3, so partials are safe) ----
        if (tid < 64) {
            float p = partials[0][tid] + partials[1][tid]
                    + partials[2][tid] + partials[3][tid] + bias2;
            long e = (long)t * 64 + tid;
            if (e < NE) out[e] = 1.0f / (1.0f + expf(-p));
        }
    }
}

// Fallback (ws too small for mirrors): f32 gather, fp16 x, fp16 w1t (128 KB ws)
__global__ __launch_bounds__(256) void edge_mlp_f32(
    const float* __restrict__ z, const float* __restrict__ z2,
    const int* __restrict__ edge,
    const _Float16* __restrict__ w1t,
    const float* __restrict__ b1, const float* __restrict__ W2,
    const float* __restrict__ b2, float* __restrict__ out)
{
    __shared__ _Float16 xs[64 * 256];
    __shared__ float partials[4][64];
    const int tid = threadIdx.x, lane = tid & 63, wv = tid >> 6;
    const int l15 = lane & 15, l4 = lane >> 4;
    const long eb0 = (long)blockIdx.x * 64;
    {
        const int hz = lane >> 5, c4 = lane & 31;
        const float* base = hz ? z2 : z;
        for (int i = 0; i < 16; ++i) {
            int el = (wv << 4) + i;
            long ee = eb0 + el; if (ee >= NE) ee = NE - 1;
            long s = edge[ee], d = edge[NE + ee];
            float4 a = *reinterpret_cast<const float4*>(base + s * ND + (c4 << 2));
            float4 b = *reinterpret_cast<const float4*>(base + d * ND + (c4 << 2));
            _Float16 p[4] = {(_Float16)(a.x * b.x), (_Float16)(a.y * b.y),
                             (_Float16)(a.z * b.z), (_Float16)(a.w * b.w)};
            int col0 = (hz << 7) + (c4 << 2);
            int o = el * 256 + (col0 ^ ((el & 7) << 3));
            xs[o] = p[0]; xs[o + 1] = p[1]; xs[o + 2] = p[2]; xs[o + 3] = p[3];
        }
    }
    __syncthreads();
    f32x4 acc[4][4];
    for (int m = 0; m < 4; ++m) for (int n = 0; n < 4; ++n) acc[m][n] = (f32x4){0,0,0,0};
    const int ncol0 = wv * 64 + l15;
    for (int ks = 0; ks < 8; ++ks) {
        const int k0 = ks * 32 + l4 * 8;
        half8 a[4], b[4];
        for (int m = 0; m < 4; ++m) {
            int row = m * 16 + l15;
            a[m] = *reinterpret_cast<const half8*>(&xs[row * 256 + (k0 ^ ((row & 7) << 3))]);
        }
        for (int n = 0; n < 4; ++n)
            b[n] = *reinterpret_cast<const half8*>(w1t + (long)(ncol0 + n * 16) * 256 + k0);
        for (int m = 0; m < 4; ++m) for (int n = 0; n < 4; ++n)
            acc[m][n] = __builtin_amdgcn_mfma_f32_16x16x32_f16(a[m], b[n], acc[m][n], 0, 0, 0);
    }
    float b1v[4], w2v[4];
    for (int n = 0; n < 4; ++n) {
        int col = wv * 64 + n * 16 + l15;
        b1v[n] = b1[col]; w2v[n] = W2[col];
    }
    for (int m = 0; m < 4; ++m) {
        float s0 = 0, s1 = 0, s2 = 0, s3 = 0;
        for (int n = 0; n < 4; ++n) {
            float h0 = fmaxf(acc[m][n][0] + b1v[n], 0.f), h1 = fmaxf(acc[m][n][1] + b1v[n], 0.f);
            float h2 = fmaxf(acc[m][n][2] + b1v[n], 0.f), h3 = fmaxf(acc[m][n][3] + b1v[n], 0.f);
            s0 += h0 * w2v[n]; s1 += h1 * w2v[n]; s2 += h2 * w2v[n]; s3 += h3 * w2v[n];
        }
        for (int mask = 1; mask < 16; mask <<= 1) {
            s0 += __shfl_xor(s0, mask, 64); s1 += __shfl_xor(s1, mask, 64);
            s2 += __shfl_xor(s2, mask, 64); s3 += __shfl_xor(s3, mask, 64);
        }
        if (l15 == 0) {
            int rb = m * 16 + l4 * 4;
            partials[wv][rb] = s0; partials[wv][rb + 1] = s1;
            partials[wv][rb + 2] = s2; partials[wv][rb + 3] = s3;
        }
    }
    __syncthreads();
    if (tid < 64) {
        float p = partials[0][tid] + partials[1][tid] + partials[2][tid]
                + partials[3][tid] + b2[0];
        long e = eb0 + tid;
        if (e < NE) out[e] = 1.0f / (1.0f + expf(-p));
    }
}

extern "C" void kernel_launch(void* const* d_in, const int* in_sizes, int n_in,
                              void* d_out, int out_size, void* d_ws, size_t ws_size,
                              hipStream_t stream)
{
    const float* z  = (const float*)d_in[0];
    const float* z2 = (const float*)d_in[1];
    const int*  edge = (const int*)d_in[2];
    const float* W1 = (const float*)d_in[3];
    const float* b1 = (const float*)d_in[4];
    const float* W2 = (const float*)d_in[5];
    const float* b2 = (const float*)d_in[6];
    float* out = (float*)d_out;

    const size_t zh_bytes = (size_t)NNODES * ND * 2;         // 25.6 MB each
    const size_t need = 2 * zh_bytes + 256 * 256 * 2;        // + w1t
    const bool mirrors = (ws_size >= need);

    _Float16* zh  = (_Float16*)d_ws;
    _Float16* z2h = (_Float16*)((char*)d_ws + zh_bytes);
    _Float16* w1t = mirrors
        ? (_Float16*)((char*)d_ws + 2 * zh_bytes)
        : (_Float16*)d_ws;

    prep_w1t_kernel<<<256, 256, 0, stream>>>(W1, w1t);
    if (mirrors) {
        prep_zh_kernel<<<12500, 256, 0, stream>>>(z, z2, zh, z2h);
        const int nblk = (NT + TPB - 1) / TPB;   // 977
        edge_mlp_pipe<<<nblk, 512, 0, stream>>>(
            zh, z2h, edge, w1t, b1, W2, b2, out);
    } else {
        edge_mlp_f32<<<NT, 256, 0, stream>>>(
            z, z2, edge, w1t, b1, W2, b2, out);
    }
}